// Round 2
// baseline (94.716 us; speedup 1.0000x reference)
//
#include <hip/hip_runtime.h>

typedef float f32x4 __attribute__((ext_vector_type(4)));

// LIF forward: v = decay*v + x[t]; s = (v>=1); hard reset v=0 on spike.
// One thread owns 8 consecutive channels (two float4 chains) so that
//  (a) the whole grid is co-resident (no dispatch tail), and
//  (b) two independent loads are in flight per iteration.
__global__ __launch_bounds__(256) void lif_fwd_kernel(
    const f32x4* __restrict__ x,      // [T, N/4] as float4
    const f32x4* __restrict__ w4,     // [C/4]
    const f32x4* __restrict__ v0,     // [N/4]
    f32x4* __restrict__ out,          // [T, N/4]
    int n8, int c8, int T)
{
    int i = blockIdx.x * blockDim.x + threadIdx.x;
    if (i >= n8) return;

    const size_t j0 = (size_t)2 * i;       // float4 index of first half
    const size_t j1 = j0 + 1;
    const size_t stride4 = (size_t)2 * n8;  // float4s per timestep

    // decay = 1 - sigmoid(w), per channel (once, off the hot path)
    const int wg = (i % c8) * 2;
    f32x4 w0 = w4[wg], w1 = w4[wg + 1];
    f32x4 d0, d1;
#pragma unroll
    for (int k = 0; k < 4; ++k) {
        d0[k] = 1.0f - 1.0f / (1.0f + expf(-w0[k]));
        d1[k] = 1.0f - 1.0f / (1.0f + expf(-w1[k]));
    }

    f32x4 va = v0[j0];
    f32x4 vb = v0[j1];

    for (int t = 0; t < T; ++t) {
        const size_t base = (size_t)t * stride4;
        f32x4 xa = __builtin_nontemporal_load(&x[base + j0]);
        f32x4 xb = __builtin_nontemporal_load(&x[base + j1]);
        f32x4 sa, sb;
#pragma unroll
        for (int k = 0; k < 4; ++k) {
            // v = decay*v + x  (round-per-op, no FMA contraction: match numpy)
            va[k] = __fadd_rn(__fmul_rn(d0[k], va[k]), xa[k]);
            sa[k] = (va[k] >= 1.0f) ? 1.0f : 0.0f;
            va[k] = (va[k] >= 1.0f) ? 0.0f : va[k];
        }
#pragma unroll
        for (int k = 0; k < 4; ++k) {
            vb[k] = __fadd_rn(__fmul_rn(d1[k], vb[k]), xb[k]);
            sb[k] = (vb[k] >= 1.0f) ? 1.0f : 0.0f;
            vb[k] = (vb[k] >= 1.0f) ? 0.0f : vb[k];
        }
        __builtin_nontemporal_store(sa, &out[base + j0]);
        __builtin_nontemporal_store(sb, &out[base + j1]);
    }
}

extern "C" void kernel_launch(void* const* d_in, const int* in_sizes, int n_in,
                              void* d_out, int out_size, void* d_ws, size_t ws_size,
                              hipStream_t stream) {
    const float* x      = (const float*)d_in[0];   // [T,B,S,C]
    const float* w      = (const float*)d_in[1];   // [C]
    const float* v_init = (const float*)d_in[2];   // [B,S,C]
    float* out = (float*)d_out;                    // [T,B,S,C]

    const int C  = in_sizes[1];
    const int N  = in_sizes[2];                    // B*S*C
    const int T  = in_sizes[0] / N;
    const int n8 = N / 8;                          // C=512, divisible by 8
    const int c8 = C / 8;

    dim3 block(256);
    dim3 grid((n8 + block.x - 1) / block.x);
    lif_fwd_kernel<<<grid, block, 0, stream>>>(
        (const f32x4*)x, (const f32x4*)w, (const f32x4*)v_init,
        (f32x4*)out, n8, c8, T);
}

// Round 3
// 87.737 us; speedup vs baseline: 1.0795x; 1.0795x over previous
//
#include <hip/hip_runtime.h>

typedef float f32x4 __attribute__((ext_vector_type(4)));

// LIF forward: v = decay*v + x[t]; s = (v>=1); hard reset v=0 on spike.
// Dual-chain variant: thread handles float4 j and j + n4/2 so that every
// load/store instruction stays stride-1 coalesced across the wave, while
// halving the grid (fully co-resident) and doubling loads in flight.
__global__ __launch_bounds__(256) void lif_fwd_dual(
    const f32x4* __restrict__ x,      // [T, n4]
    const f32x4* __restrict__ w4,     // [c4]
    const f32x4* __restrict__ v0,     // [n4]
    f32x4* __restrict__ out,          // [T, n4]
    int n4, int c4, int T)
{
    const int half = n4 >> 1;
    int i = blockIdx.x * blockDim.x + threadIdx.x;
    if (i >= half) return;

    const size_t j0 = (size_t)i;
    const size_t j1 = (size_t)i + half;   // half % c4 == 0 -> same channel phase

    // decay = 1 - sigmoid(w); identical for both chains (half is a multiple of c4)
    f32x4 wv = w4[i % c4];
    f32x4 dec;
#pragma unroll
    for (int k = 0; k < 4; ++k)
        dec[k] = 1.0f - 1.0f / (1.0f + expf(-wv[k]));

    f32x4 va = v0[j0];
    f32x4 vb = v0[j1];

    for (int t = 0; t < T; ++t) {
        const size_t base = (size_t)t * n4;
        f32x4 xa = x[base + j0];
        f32x4 xb = x[base + j1];
        f32x4 sa, sb;
#pragma unroll
        for (int k = 0; k < 4; ++k) {
            // v = decay*v + x (round-per-op, no FMA contraction: match numpy)
            va[k] = __fadd_rn(__fmul_rn(dec[k], va[k]), xa[k]);
            sa[k] = (va[k] >= 1.0f) ? 1.0f : 0.0f;
            va[k] = (va[k] >= 1.0f) ? 0.0f : va[k];
            vb[k] = __fadd_rn(__fmul_rn(dec[k], vb[k]), xb[k]);
            sb[k] = (vb[k] >= 1.0f) ? 1.0f : 0.0f;
            vb[k] = (vb[k] >= 1.0f) ? 0.0f : vb[k];
        }
        out[base + j0] = sa;
        out[base + j1] = sb;
    }
}

// Fallback (R1 structure): one float4 per thread, used if shape assumptions fail.
__global__ __launch_bounds__(256) void lif_fwd_single(
    const f32x4* __restrict__ x, const f32x4* __restrict__ w4,
    const f32x4* __restrict__ v0, f32x4* __restrict__ out,
    int n4, int c4, int T)
{
    int i = blockIdx.x * blockDim.x + threadIdx.x;
    if (i >= n4) return;
    f32x4 wv = w4[i % c4];
    f32x4 dec;
#pragma unroll
    for (int k = 0; k < 4; ++k)
        dec[k] = 1.0f - 1.0f / (1.0f + expf(-wv[k]));
    f32x4 v = v0[i];
    for (int t = 0; t < T; ++t) {
        const size_t base = (size_t)t * n4;
        f32x4 xt = x[base + i];
        f32x4 s;
#pragma unroll
        for (int k = 0; k < 4; ++k) {
            v[k] = __fadd_rn(__fmul_rn(dec[k], v[k]), xt[k]);
            s[k] = (v[k] >= 1.0f) ? 1.0f : 0.0f;
            v[k] = (v[k] >= 1.0f) ? 0.0f : v[k];
        }
        out[base + i] = s;
    }
}

extern "C" void kernel_launch(void* const* d_in, const int* in_sizes, int n_in,
                              void* d_out, int out_size, void* d_ws, size_t ws_size,
                              hipStream_t stream) {
    const float* x      = (const float*)d_in[0];   // [T,B,S,C]
    const float* w      = (const float*)d_in[1];   // [C]
    const float* v_init = (const float*)d_in[2];   // [B,S,C]
    float* out = (float*)d_out;                    // [T,B,S,C]

    const int C  = in_sizes[1];
    const int N  = in_sizes[2];                    // B*S*C
    const int T  = in_sizes[0] / N;
    const int n4 = N / 4;
    const int c4 = C / 4;

    const int half = n4 / 2;
    const bool dual_ok = (n4 % 2 == 0) && (half % c4 == 0);

    dim3 block(256);
    if (dual_ok) {
        dim3 grid((half + block.x - 1) / block.x);
        lif_fwd_dual<<<grid, block, 0, stream>>>(
            (const f32x4*)x, (const f32x4*)w, (const f32x4*)v_init,
            (f32x4*)out, n4, c4, T);
    } else {
        dim3 grid((n4 + block.x - 1) / block.x);
        lif_fwd_single<<<grid, block, 0, stream>>>(
            (const f32x4*)x, (const f32x4*)w, (const f32x4*)v_init,
            (f32x4*)out, n4, c4, T);
    }
}

// Round 4
// 76.348 us; speedup vs baseline: 1.2406x; 1.1492x over previous
//
#include <hip/hip_runtime.h>

typedef float f32x4 __attribute__((ext_vector_type(4)));

// LIF forward: v = decay*v + x[t]; s = (v>=1); hard reset v=0 on spike.
// R1 layout (one float4 per thread, stride-1 coalesced) + non-temporal
// loads/stores: x and out are pure streams (never reused), and NT stores
// avoid any write-allocate traffic for `out` lines in L2.
__global__ __launch_bounds__(256) void lif_fwd_kernel(
    const f32x4* __restrict__ x,      // [T, n4]
    const f32x4* __restrict__ w4,     // [c4]
    const f32x4* __restrict__ v0,     // [n4]
    f32x4* __restrict__ out,          // [T, n4]
    int n4, int c4, int T)
{
    int i = blockIdx.x * blockDim.x + threadIdx.x;
    if (i >= n4) return;

    // decay = 1 - sigmoid(w), per channel (once, off the hot path)
    f32x4 wv = w4[i % c4];
    f32x4 dec;
#pragma unroll
    for (int k = 0; k < 4; ++k)
        dec[k] = 1.0f - 1.0f / (1.0f + expf(-wv[k]));

    f32x4 v = v0[i];

    for (int t = 0; t < T; ++t) {
        const size_t idx = (size_t)t * n4 + i;
        f32x4 xt = __builtin_nontemporal_load(&x[idx]);
        f32x4 s;
#pragma unroll
        for (int k = 0; k < 4; ++k) {
            // v = decay*v + x (round-per-op, no FMA contraction: match numpy)
            v[k] = __fadd_rn(__fmul_rn(dec[k], v[k]), xt[k]);
            s[k] = (v[k] >= 1.0f) ? 1.0f : 0.0f;
            v[k] = (v[k] >= 1.0f) ? 0.0f : v[k];
        }
        __builtin_nontemporal_store(s, &out[idx]);
    }
}

extern "C" void kernel_launch(void* const* d_in, const int* in_sizes, int n_in,
                              void* d_out, int out_size, void* d_ws, size_t ws_size,
                              hipStream_t stream) {
    const float* x      = (const float*)d_in[0];   // [T,B,S,C]
    const float* w      = (const float*)d_in[1];   // [C]
    const float* v_init = (const float*)d_in[2];   // [B,S,C]
    float* out = (float*)d_out;                    // [T,B,S,C]

    const int C  = in_sizes[1];
    const int N  = in_sizes[2];                    // B*S*C
    const int T  = in_sizes[0] / N;
    const int n4 = N / 4;
    const int c4 = C / 4;

    dim3 block(256);
    dim3 grid((n4 + block.x - 1) / block.x);
    lif_fwd_kernel<<<grid, block, 0, stream>>>(
        (const f32x4*)x, (const f32x4*)w, (const f32x4*)v_init,
        (f32x4*)out, n4, c4, T);
}